// Round 6
// baseline (36818.793 us; speedup 1.0000x reference)
//
#include <hip/hip_runtime.h>
#include <hip/hip_bf16.h>
#include <stdint.h>

// FT-Transformer forward, MI355X gfx950. Round 6:
//  - GEMM block tile 128x256 (wave = 64x128, 4x8 MFMA tiles, acc 128 AGPR):
//    AI 64 -> 85 FLOP/B (L2 per-CU delivery was the round-5 ceiling), loads/MFMA 0.375.
//    __launch_bounds__(256,2): ~240 regs/wave -> 2 waves/SIMD.
//  - W0 padded to N=1536 pair-space (zeros -> ReGLU 0), regl 768 wide, W1 K=768.
//  - everything else (frag layout, LDS-free, XCD remap, attention, LN) = round 5.

typedef __hip_bfloat16 bf16_t;
typedef __attribute__((ext_vector_type(8))) __bf16 bf16x8;
typedef __attribute__((ext_vector_type(4))) float floatx4;

constexpr int M_ROWS = 16512;          // 128 * 129
constexpr float SQRT_EMB_F = 22.627416997969522f;  // scores DIVIDED by emb**-0.5

__device__ __forceinline__ floatx4 mfma16(bf16x8 a, bf16x8 b, floatx4 c) {
  return __builtin_amdgcn_mfma_f32_16x16x32_bf16(a, b, c, 0, 0, 0);
}

// element offset of the 16B chunk holding (m, k..k+7) in fragment-tiled [M/16][KT][512]
__device__ __forceinline__ size_t frag_chunk(int m, int k, int KT) {
  return ((size_t)(m >> 4) * KT + (k >> 5)) * 512 + (m & 15) * 8 + 128 * ((k >> 3) & 3);
}
// element offset of scalar (m, k)
__device__ __forceinline__ size_t frag_elem(int m, int k, int KT) {
  return frag_chunk(m, k, KT) + (k & 7);
}

// ---------------- weight transform: W [L][K][N] fp32 -> frag-tiled bf16 [L][NP/16][KP/32][512]
// PERM=1: output col n maps to source col (n&1) ? 682+(n>>1) : (n>>1)  (ReGLU pairing)
template <int PERM>
__global__ __launch_bounds__(256) void transpose_cvt(const float* __restrict__ W,
    bf16_t* __restrict__ WT, int K, int N, int KP, int NP)
{
  __shared__ float tile[32][33];
  int k0 = blockIdx.x * 32, n0 = blockIdx.y * 32;
  const float* Wl = W + (size_t)blockIdx.z * K * N;
  bf16_t* WTl = WT + (size_t)blockIdx.z * NP * KP;
  const int KT = KP >> 5;
  #pragma unroll
  for (int r = 0; r < 32; r += 8) {
    int k = k0 + threadIdx.y + r, n = n0 + threadIdx.x;
    int srcn = PERM ? ((n & 1) ? 682 + (n >> 1) : (n >> 1)) : n;
    int valid = (k < K) && (PERM ? (n < 1364) : (n < N));
    tile[threadIdx.y + r][threadIdx.x] = valid ? Wl[(size_t)k * N + srcn] : 0.f;
  }
  __syncthreads();
  #pragma unroll
  for (int r = 0; r < 32; r += 8) {
    int n = n0 + threadIdx.y + r, k = k0 + threadIdx.x;
    if (n < NP && k < KP)
      WTl[frag_elem(n, k, KT)] = __float2bfloat16(tile[threadIdx.x][threadIdx.y + r]);
  }
}

// ---------------- feature tokenizer: wave per row; h row-major fp32 + ab frag bf16 ----------------
__global__ __launch_bounds__(256) void tokenizer_kernel(const float* __restrict__ x,
    const float* __restrict__ tok_w, const float* __restrict__ tok_b,
    const float* __restrict__ cat_emb, float* __restrict__ h, bf16_t* __restrict__ ab)
{
  int row = blockIdx.x * 4 + (threadIdx.x >> 6);
  int lane = threadIdx.x & 63, e0 = lane * 8;
  int b = row / 129, t = row - b * 129;
  float v[8];
  if (t == 0) {
    #pragma unroll
    for (int u = 0; u < 8; u++) v[u] = tok_w[e0 + u];
  } else if (t <= 100) {
    float xv = x[(size_t)b * 128 + 28 + (t - 1)];
    const float* wp = tok_w + (size_t)t * 512 + e0;
    const float* bp = tok_b + (size_t)(t - 1) * 512 + e0;
    #pragma unroll
    for (int u = 0; u < 8; u++) v[u] = wp[u] * xv + bp[u];
  } else {
    int j = t - 101;
    int idx = (int)x[(size_t)b * 128 + j] + 100 * j;
    const float* cp = cat_emb + (size_t)idx * 512 + e0;
    const float* bp = tok_b + (size_t)(t - 1) * 512 + e0;
    #pragma unroll
    for (int u = 0; u < 8; u++) v[u] = cp[u] + bp[u];
  }
  float* hr = h + (size_t)row * 512 + e0;
  #pragma unroll
  for (int u = 0; u < 8; u++) hr[u] = v[u];
  bf16x8 o8;
  #pragma unroll
  for (int u = 0; u < 8; u++) o8[u] = (__bf16)__float2bfloat16(v[u]);
  *(bf16x8*)(ab + ((size_t)(row >> 4) * 16 + (lane >> 2)) * 512 + (row & 15) * 8 + 128 * (lane & 3)) = o8;
}

// ---------------- layernorm: one wave per row; out = frag-tiled bf16 (KT=16) ----------------
__global__ __launch_bounds__(256) void ln_kernel(const float* __restrict__ hin,
    bf16_t* __restrict__ out, const float* __restrict__ g, const float* __restrict__ bta)
{
  int row = blockIdx.x * 4 + (threadIdx.x >> 6);
  int lane = threadIdx.x & 63;
  const float* hr = hin + (size_t)row * 512 + lane * 8;
  float4 v0 = *(const float4*)hr;
  float4 v1 = *(const float4*)(hr + 4);
  float s = v0.x + v0.y + v0.z + v0.w + v1.x + v1.y + v1.z + v1.w;
  float q = v0.x * v0.x + v0.y * v0.y + v0.z * v0.z + v0.w * v0.w
          + v1.x * v1.x + v1.y * v1.y + v1.z * v1.z + v1.w * v1.w;
  #pragma unroll
  for (int o = 1; o < 64; o <<= 1) { s += __shfl_xor(s, o); q += __shfl_xor(q, o); }
  float mean = s * (1.f / 512.f);
  float var = q * (1.f / 512.f) - mean * mean;
  float rstd = rsqrtf(var + 1e-5f);
  float4 g0 = *(const float4*)(g + lane * 8);
  float4 g1 = *(const float4*)(g + lane * 8 + 4);
  float4 b0v = *(const float4*)(bta + lane * 8);
  float4 b1v = *(const float4*)(bta + lane * 8 + 4);
  bf16x8 o8;
  o8[0] = (__bf16)__float2bfloat16((v0.x - mean) * rstd * g0.x + b0v.x);
  o8[1] = (__bf16)__float2bfloat16((v0.y - mean) * rstd * g0.y + b0v.y);
  o8[2] = (__bf16)__float2bfloat16((v0.z - mean) * rstd * g0.z + b0v.z);
  o8[3] = (__bf16)__float2bfloat16((v0.w - mean) * rstd * g0.w + b0v.w);
  o8[4] = (__bf16)__float2bfloat16((v1.x - mean) * rstd * g1.x + b1v.x);
  o8[5] = (__bf16)__float2bfloat16((v1.y - mean) * rstd * g1.y + b1v.y);
  o8[6] = (__bf16)__float2bfloat16((v1.z - mean) * rstd * g1.z + b1v.z);
  o8[7] = (__bf16)__float2bfloat16((v1.w - mean) * rstd * g1.w + b1v.w);
  *(bf16x8*)(out + ((size_t)(row >> 4) * 16 + (lane >> 2)) * 512 + (row & 15) * 8 + 128 * (lane & 3)) = o8;
}

// ---------------- frag GEMM 128x256: C[M,N] = A * BT^T + bias, no LDS, no barriers ----------------
// A frag-tiled [M/16][K/32][512]; BT frag-tiled [N/16][K/32][512]. grid (N/256, M/128).
// Wave = 64x128: 4 m-tiles x 8 n-tiles, acc 4x8 floatx4 (128 AGPR).
// MODE 0: out bf16 frag-tiled (KT_out = N/32).
// MODE 1: out fp32 row-major = resid + acc + bias (N==512).
// MODE 2: ReGLU: paired cols (a=even,b=odd), out bf16 frag-tiled [M/16][(N/2)/32][512].
template <int MODE>
__global__ __launch_bounds__(256, 2) void gemm_frag(const bf16_t* __restrict__ A,
    const bf16_t* __restrict__ BT, const float* __restrict__ bias, int biasN,
    const float* __restrict__ resid, void* __restrict__ outp, int K, int N)
{
  // XCD-aware remap: blocks with lin%8==x get a contiguous idx chunk
  const int total = gridDim.x * gridDim.y;
  const int lin = blockIdx.y * gridDim.x + blockIdx.x;
  const int xcd = lin & 7, kb2 = lin >> 3;
  const int qch = total >> 3, rch = total & 7;
  const int idx = xcd * qch + (xcd < rch ? xcd : rch) + kb2;
  const int bm = idx / gridDim.x;
  const int bn = idx - bm * gridDim.x;
  const int m0 = bm * 128, n0 = bn * 256;

  const int tid = threadIdx.x;
  const int w = tid >> 6, l = tid & 63, l15 = l & 15, quad = l >> 4;
  const int wm = (w >> 1) * 64, wn = (w & 1) * 128;
  const int KT = K >> 5;

  const bf16_t* pa = A  + ((size_t)((m0 + wm) >> 4) * KT) * 512 + l * 8;
  const bf16_t* pb = BT + ((size_t)((n0 + wn) >> 4) * KT) * 512 + l * 8;
  const size_t ts = (size_t)KT * 512;   // m/n tile stride (elements)

  bf16x8 af[2][4], bg[2][8];
  #pragma unroll
  for (int i = 0; i < 4; i++) af[0][i] = *(const bf16x8*)(pa + i * ts);
  #pragma unroll
  for (int j = 0; j < 8; j++) bg[0][j] = *(const bf16x8*)(pb + j * ts);

  floatx4 z4 = {0.f, 0.f, 0.f, 0.f};
  floatx4 acc[4][8];
  #pragma unroll
  for (int i = 0; i < 4; i++)
    #pragma unroll
    for (int j = 0; j < 8; j++) acc[i][j] = z4;

  const int T = KT;
  for (int t = 0; t < T; t++) {
    const int cb = t & 1, nb = cb ^ 1;
    if (t + 1 < T) {
      const size_t ko = (size_t)(t + 1) * 512;
      #pragma unroll
      for (int i = 0; i < 4; i++) af[nb][i] = *(const bf16x8*)(pa + i * ts + ko);
      #pragma unroll
      for (int j = 0; j < 8; j++) bg[nb][j] = *(const bf16x8*)(pb + j * ts + ko);
    }
    #pragma unroll
    for (int i = 0; i < 4; i++)
      #pragma unroll
      for (int j = 0; j < 8; j++)
        acc[i][j] = mfma16(af[cb][i], bg[cb][j], acc[i][j]);
  }

  #pragma unroll
  for (int j = 0; j < 8; j++) {
    int col = n0 + wn + j * 16 + l15;
    float bv = 0.f;
    if (MODE == 2) {
      if (col < biasN) bv = bias[(col & 1) ? 682 + (col >> 1) : (col >> 1)];
    } else {
      if (col < biasN) bv = bias[col];
    }
    #pragma unroll
    for (int i = 0; i < 4; i++) {
      int row_b = m0 + wm + i * 16 + quad * 4;
      #pragma unroll
      for (int r = 0; r < 4; r++) {
        float v = acc[i][j][r] + bv;
        int m = row_b + r;
        if (MODE == 2) {
          float other = __shfl_xor(v, 1);
          if (!(l15 & 1)) {
            int c2 = col >> 1;
            ((bf16_t*)outp)[frag_elem(m, c2, (N >> 1) >> 5)] =
                __float2bfloat16(v * fmaxf(other, 0.f));
          }
        } else if (MODE == 1) {
          size_t idx2 = (size_t)m * N + col;
          ((float*)outp)[idx2] = v + resid[idx2];
        } else {
          ((bf16_t*)outp)[frag_elem(m, col, N >> 5)] = __float2bfloat16(v);
        }
      }
    }
  }
}

// ---------------- fused attention: one block per (batch, head) ----------------
// qkv frag-tiled over [M, 1536] (KT=48); head hh: q at col hh*192, k +64, v +128.
constexpr int SP = 160;  // S=129 padded to 5*32
__global__ __launch_bounds__(256) void attn_kernel(const bf16_t* __restrict__ qkv,
                                                   bf16_t* __restrict__ attnout)
{
  __shared__ bf16_t vt_lds[64 * SP];   // [d][s_kv]
  __shared__ float sc[32 * SP];        // scores; p (bf16) overlays
  bf16_t* p_lds = (bf16_t*)sc;
  __bf16* vt_raw = (__bf16*)vt_lds;

  const int bh = blockIdx.x, b = bh >> 3, hh = bh & 7;
  const int tid = threadIdx.x;
  const int w = tid >> 6, l = tid & 63, l15 = l & 15, quad = l >> 4;
  const int rbase = b * 129;

  for (int i = tid; i < SP * 64 / 2; i += 256) ((unsigned int*)vt_lds)[i] = 0u;
  __syncthreads();
  for (int c = tid; c < 129 * 8; c += 256) {
    int s = c >> 3, ch = c & 7;
    bf16x8 tv = *(const bf16x8*)(qkv + frag_chunk(rbase + s, hh * 192 + 128 + ch * 8, 48));
    #pragma unroll
    for (int j = 0; j < 8; j++) vt_raw[(size_t)(ch * 8 + j) * SP + s] = tv[j];
  }
  __syncthreads();

  for (int qt = 0; qt < 5; qt++) {
    bf16x8 zq = {};
    bf16x8 aq[2][2];
    #pragma unroll
    for (int mt = 0; mt < 2; mt++) {
      int m = qt * 32 + mt * 16 + l15;
      #pragma unroll
      for (int t = 0; t < 2; t++)
        aq[mt][t] = (m < 129)
            ? *(const bf16x8*)(qkv + frag_chunk(rbase + m, hh * 192 + t * 32 + quad * 8, 48)) : zq;
    }
    for (int nt = w; nt < 10; nt += 4) {
      int krow = nt * 16 + l15;
      floatx4 a0 = {0.f, 0.f, 0.f, 0.f}, a1 = {0.f, 0.f, 0.f, 0.f};
      #pragma unroll
      for (int t = 0; t < 2; t++) {
        bf16x8 kf = (krow < 129)
            ? *(const bf16x8*)(qkv + frag_chunk(rbase + krow, hh * 192 + 64 + t * 32 + quad * 8, 48))
            : zq;
        a0 = mfma16(aq[0][t], kf, a0);
        a1 = mfma16(aq[1][t], kf, a1);
      }
      #pragma unroll
      for (int r = 0; r < 4; r++) {
        sc[(quad * 4 + r) * SP + nt * 16 + l15]      = a0[r] * SQRT_EMB_F;
        sc[(16 + quad * 4 + r) * SP + nt * 16 + l15] = a1[r] * SQRT_EMB_F;
      }
    }
    __syncthreads();

    // double softmax, 8 threads per row
    {
      int row = tid >> 3, sub = tid & 7;
      float vv[20];
      float mx = -1e30f;
      #pragma unroll
      for (int c = 0; c < 20; c++) {
        int j = sub + c * 8;
        vv[c] = (j < 129) ? sc[row * SP + j] : -1e30f;
        mx = fmaxf(mx, vv[c]);
      }
      #pragma unroll
      for (int o = 1; o < 8; o <<= 1) mx = fmaxf(mx, __shfl_xor(mx, o, 8));
      float sum = 0.f;
      #pragma unroll
      for (int c = 0; c < 20; c++) {
        int j = sub + c * 8;
        vv[c] = (j < 129) ? __expf(vv[c] - mx) : 0.f;
        sum += vv[c];
      }
      #pragma unroll
      for (int o = 1; o < 8; o <<= 1) sum += __shfl_xor(sum, o, 8);
      float inv = 1.f / sum;
      float mx2 = 0.f;
      #pragma unroll
      for (int c = 0; c < 20; c++) { vv[c] *= inv; mx2 = fmaxf(mx2, vv[c]); }
      #pragma unroll
      for (int o = 1; o < 8; o <<= 1) mx2 = fmaxf(mx2, __shfl_xor(mx2, o, 8));
      float sum2 = 0.f;
      #pragma unroll
      for (int c = 0; c < 20; c++) {
        int j = sub + c * 8;
        vv[c] = (j < 129) ? __expf(vv[c] - mx2) : 0.f;
        sum2 += vv[c];
      }
      #pragma unroll
      for (int o = 1; o < 8; o <<= 1) sum2 += __shfl_xor(sum2, o, 8);
      float inv2 = 1.f / sum2;
      __syncthreads();
      #pragma unroll
      for (int c = 0; c < 20; c++) {
        int j = sub + c * 8;
        p_lds[row * SP + j] = __float2bfloat16(vv[c] * inv2);  // pads -> 0
      }
    }
    __syncthreads();

    // PV: o[32,64] = p[32,160] @ v[160,64]; store attno in frag layout (KT=16)
    {
      int mt = w >> 1, nt0 = (w & 1) * 2;
      floatx4 oacc[2];
      oacc[0] = floatx4{0.f, 0.f, 0.f, 0.f};
      oacc[1] = floatx4{0.f, 0.f, 0.f, 0.f};
      #pragma unroll
      for (int t = 0; t < 5; t++) {
        bf16x8 pf = *(const bf16x8*)&p_lds[(mt * 16 + l15) * SP + t * 32 + quad * 8];
        #pragma unroll
        for (int n = 0; n < 2; n++) {
          bf16x8 vf = *(const bf16x8*)&vt_lds[((nt0 + n) * 16 + l15) * SP + t * 32 + quad * 8];
          oacc[n] = mfma16(pf, vf, oacc[n]);
        }
      }
      #pragma unroll
      for (int n = 0; n < 2; n++)
        #pragma unroll
        for (int r = 0; r < 4; r++) {
          int sq = qt * 32 + mt * 16 + quad * 4 + r;
          if (sq < 129) {
            int cc = hh * 64 + (nt0 + n) * 16 + l15;
            attnout[frag_elem(rbase + sq, cc, 16)] = __float2bfloat16(oacc[n][r]);
          }
        }
    }
    __syncthreads();
  }
}

// ---------------- output: CLS rows ----------------
__global__ __launch_bounds__(256) void out_copy(const float* __restrict__ h,
                                                float* __restrict__ out)
{
  int b = blockIdx.x, e = threadIdx.x;
  out[(size_t)b * 512 + e]       = h[(size_t)b * 129 * 512 + e];
  out[(size_t)b * 512 + e + 256] = h[(size_t)b * 129 * 512 + e + 256];
}

// ---------------- host launcher ----------------
extern "C" void kernel_launch(void* const* d_in, const int* in_sizes, int n_in,
                              void* d_out, int out_size, void* d_ws, size_t ws_size,
                              hipStream_t stream)
{
  const float* x       = (const float*)d_in[0];
  const float* tok_w   = (const float*)d_in[1];
  const float* tok_b   = (const float*)d_in[2];
  const float* cat_emb = (const float*)d_in[3];
  const float* Wqkv    = (const float*)d_in[4];
  const float* bqkv    = (const float*)d_in[5];
  const float* Wout    = (const float*)d_in[6];
  const float* bout    = (const float*)d_in[7];
  const float* W0      = (const float*)d_in[8];
  const float* b0      = (const float*)d_in[9];
  const float* W1      = (const float*)d_in[10];
  const float* b1      = (const float*)d_in[11];
  const float* ln0_g   = (const float*)d_in[12];
  const float* ln0_b   = (const float*)d_in[13];
  const float* ln1_g   = (const float*)d_in[14];
  const float* ln1_b   = (const float*)d_in[15];

  size_t off = 0;
  char* base = (char*)d_ws;
  auto alloc = [&](size_t n) { char* p = base + off; off += (n + 255) & ~(size_t)255; return p; };
  float*  h     = (float*) alloc((size_t)M_ROWS * 512 * 4);
  bf16_t* ab    = (bf16_t*)alloc((size_t)M_ROWS * 512 * 2);   // LN out, frag KT=16
  bf16_t* qkv   = (bf16_t*)alloc((size_t)M_ROWS * 1536 * 2);  // frag KT=48
  bf16_t* attno = (bf16_t*)alloc((size_t)M_ROWS * 512 * 2);   // frag KT=16
  bf16_t* regl  = (bf16_t*)alloc((size_t)M_ROWS * 768 * 2);   // frag KT=24
  bf16_t* WqkvT = (bf16_t*)alloc((size_t)6 * 1536 * 512 * 2);
  bf16_t* WoutT = (bf16_t*)alloc((size_t)6 * 512 * 512 * 2);
  bf16_t* W0T   = (bf16_t*)alloc((size_t)6 * 1536 * 512 * 2);  // pair-interleaved, padded
  bf16_t* W1T   = (bf16_t*)alloc((size_t)6 * 512 * 768 * 2);   // K padded to 768
  (void)ws_size; (void)in_sizes; (void)n_in; (void)out_size;

  dim3 tb(32, 8, 1);
  transpose_cvt<0><<<dim3(16, 48, 6), tb, 0, stream>>>(Wqkv, WqkvT, 512, 1536, 512, 1536);
  transpose_cvt<0><<<dim3(16, 16, 6), tb, 0, stream>>>(Wout, WoutT, 512, 512, 512, 512);
  transpose_cvt<1><<<dim3(16, 48, 6), tb, 0, stream>>>(W0, W0T, 512, 1364, 512, 1536);
  transpose_cvt<0><<<dim3(24, 16, 6), tb, 0, stream>>>(W1, W1T, 682, 512, 768, 512);

  tokenizer_kernel<<<M_ROWS / 4, 256, 0, stream>>>(x, tok_w, tok_b, cat_emb, h, ab);

  for (int i = 0; i < 6; i++) {
    if (i)
      ln_kernel<<<M_ROWS / 4, 256, 0, stream>>>(h, ab, ln0_g + (size_t)i * 512,
                                                ln0_b + (size_t)i * 512);
    gemm_frag<0><<<dim3(6, 129), 256, 0, stream>>>(
        ab, WqkvT + (size_t)i * 1536 * 512, bqkv + (size_t)i * 1536, 1536, nullptr, qkv, 512, 1536);
    attn_kernel<<<1024, 256, 0, stream>>>(qkv, attno);
    gemm_frag<1><<<dim3(2, 129), 256, 0, stream>>>(
        attno, WoutT + (size_t)i * 512 * 512, bout + (size_t)i * 512, 512, h, h, 512, 512);
    ln_kernel<<<M_ROWS / 4, 256, 0, stream>>>(h, ab, ln1_g + (size_t)i * 512,
                                              ln1_b + (size_t)i * 512);
    gemm_frag<2><<<dim3(6, 129), 256, 0, stream>>>(
        ab, W0T + (size_t)i * 1536 * 512, b0 + (size_t)i * 1364, 1364, nullptr, regl, 512, 1536);
    gemm_frag<1><<<dim3(2, 129), 256, 0, stream>>>(
        regl, W1T + (size_t)i * 512 * 768, b1 + (size_t)i * 512, 512, h, h, 768, 512);
  }

  out_copy<<<128, 256, 0, stream>>>(h, (float*)d_out);
}

// Round 7
// 1357.675 us; speedup vs baseline: 27.1190x; 27.1190x over previous
//
#include <hip/hip_runtime.h>
#include <hip/hip_bf16.h>
#include <stdint.h>

// FT-Transformer forward, MI355X gfx950. Round 7:
//  - GEMMs: exact round-5 structure (LDS-free frag GEMM, 128x128, 80 VGPR + 64 AGPR;
//    round-6's 128x256 spilled to scratch -> 29x regression, reverted).
//  - Attention rewritten wave-independent: 320-thread blocks (5 waves), wave w owns
//    q-tile w fully (QK^T, in-register double softmax via shfl_xor, PV). Only 2
//    barriers per block (V^T staging). LDS strides padded to 168 (336B == 20 words
//    mod 32) -> conflict-free b128 reads (was 8-way at stride 160).

typedef __hip_bfloat16 bf16_t;
typedef __attribute__((ext_vector_type(8))) __bf16 bf16x8;
typedef __attribute__((ext_vector_type(4))) float floatx4;

constexpr int M_ROWS = 16512;          // 128 * 129
constexpr float SQRT_EMB_F = 22.627416997969522f;  // scores DIVIDED by emb**-0.5

__device__ __forceinline__ floatx4 mfma16(bf16x8 a, bf16x8 b, floatx4 c) {
  return __builtin_amdgcn_mfma_f32_16x16x32_bf16(a, b, c, 0, 0, 0);
}

// element offset of the 16B chunk holding (m, k..k+7) in fragment-tiled [M/16][KT][512]
__device__ __forceinline__ size_t frag_chunk(int m, int k, int KT) {
  return ((size_t)(m >> 4) * KT + (k >> 5)) * 512 + (m & 15) * 8 + 128 * ((k >> 3) & 3);
}
// element offset of scalar (m, k)
__device__ __forceinline__ size_t frag_elem(int m, int k, int KT) {
  return frag_chunk(m, k, KT) + (k & 7);
}

// ---------------- weight transform: W [L][K][N] fp32 -> frag-tiled bf16 [L][NP/16][KP/32][512]
// PERM=1: output col n maps to source col (n&1) ? 682+(n>>1) : (n>>1)  (ReGLU pairing)
template <int PERM>
__global__ __launch_bounds__(256) void transpose_cvt(const float* __restrict__ W,
    bf16_t* __restrict__ WT, int K, int N, int KP, int NP)
{
  __shared__ float tile[32][33];
  int k0 = blockIdx.x * 32, n0 = blockIdx.y * 32;
  const float* Wl = W + (size_t)blockIdx.z * K * N;
  bf16_t* WTl = WT + (size_t)blockIdx.z * NP * KP;
  const int KT = KP >> 5;
  #pragma unroll
  for (int r = 0; r < 32; r += 8) {
    int k = k0 + threadIdx.y + r, n = n0 + threadIdx.x;
    int srcn = PERM ? ((n & 1) ? 682 + (n >> 1) : (n >> 1)) : n;
    int valid = (k < K) && (PERM ? (n < 1364) : (n < N));
    tile[threadIdx.y + r][threadIdx.x] = valid ? Wl[(size_t)k * N + srcn] : 0.f;
  }
  __syncthreads();
  #pragma unroll
  for (int r = 0; r < 32; r += 8) {
    int n = n0 + threadIdx.y + r, k = k0 + threadIdx.x;
    if (n < NP && k < KP)
      WTl[frag_elem(n, k, KT)] = __float2bfloat16(tile[threadIdx.x][threadIdx.y + r]);
  }
}

// ---------------- feature tokenizer: wave per row; h row-major fp32 + ab frag bf16 ----------------
__global__ __launch_bounds__(256) void tokenizer_kernel(const float* __restrict__ x,
    const float* __restrict__ tok_w, const float* __restrict__ tok_b,
    const float* __restrict__ cat_emb, float* __restrict__ h, bf16_t* __restrict__ ab)
{
  int row = blockIdx.x * 4 + (threadIdx.x >> 6);
  int lane = threadIdx.x & 63, e0 = lane * 8;
  int b = row / 129, t = row - b * 129;
  float v[8];
  if (t == 0) {
    #pragma unroll
    for (int u = 0; u < 8; u++) v[u] = tok_w[e0 + u];
  } else if (t <= 100) {
    float xv = x[(size_t)b * 128 + 28 + (t - 1)];
    const float* wp = tok_w + (size_t)t * 512 + e0;
    const float* bp = tok_b + (size_t)(t - 1) * 512 + e0;
    #pragma unroll
    for (int u = 0; u < 8; u++) v[u] = wp[u] * xv + bp[u];
  } else {
    int j = t - 101;
    int idx = (int)x[(size_t)b * 128 + j] + 100 * j;
    const float* cp = cat_emb + (size_t)idx * 512 + e0;
    const float* bp = tok_b + (size_t)(t - 1) * 512 + e0;
    #pragma unroll
    for (int u = 0; u < 8; u++) v[u] = cp[u] + bp[u];
  }
  float* hr = h + (size_t)row * 512 + e0;
  #pragma unroll
  for (int u = 0; u < 8; u++) hr[u] = v[u];
  bf16x8 o8;
  #pragma unroll
  for (int u = 0; u < 8; u++) o8[u] = (__bf16)__float2bfloat16(v[u]);
  *(bf16x8*)(ab + ((size_t)(row >> 4) * 16 + (lane >> 2)) * 512 + (row & 15) * 8 + 128 * (lane & 3)) = o8;
}

// ---------------- layernorm: one wave per row; out = frag-tiled bf16 (KT=16) ----------------
__global__ __launch_bounds__(256) void ln_kernel(const float* __restrict__ hin,
    bf16_t* __restrict__ out, const float* __restrict__ g, const float* __restrict__ bta)
{
  int row = blockIdx.x * 4 + (threadIdx.x >> 6);
  int lane = threadIdx.x & 63;
  const float* hr = hin + (size_t)row * 512 + lane * 8;
  float4 v0 = *(const float4*)hr;
  float4 v1 = *(const float4*)(hr + 4);
  float s = v0.x + v0.y + v0.z + v0.w + v1.x + v1.y + v1.z + v1.w;
  float q = v0.x * v0.x + v0.y * v0.y + v0.z * v0.z + v0.w * v0.w
          + v1.x * v1.x + v1.y * v1.y + v1.z * v1.z + v1.w * v1.w;
  #pragma unroll
  for (int o = 1; o < 64; o <<= 1) { s += __shfl_xor(s, o); q += __shfl_xor(q, o); }
  float mean = s * (1.f / 512.f);
  float var = q * (1.f / 512.f) - mean * mean;
  float rstd = rsqrtf(var + 1e-5f);
  float4 g0 = *(const float4*)(g + lane * 8);
  float4 g1 = *(const float4*)(g + lane * 8 + 4);
  float4 b0v = *(const float4*)(bta + lane * 8);
  float4 b1v = *(const float4*)(bta + lane * 8 + 4);
  bf16x8 o8;
  o8[0] = (__bf16)__float2bfloat16((v0.x - mean) * rstd * g0.x + b0v.x);
  o8[1] = (__bf16)__float2bfloat16((v0.y - mean) * rstd * g0.y + b0v.y);
  o8[2] = (__bf16)__float2bfloat16((v0.z - mean) * rstd * g0.z + b0v.z);
  o8[3] = (__bf16)__float2bfloat16((v0.w - mean) * rstd * g0.w + b0v.w);
  o8[4] = (__bf16)__float2bfloat16((v1.x - mean) * rstd * g1.x + b1v.x);
  o8[5] = (__bf16)__float2bfloat16((v1.y - mean) * rstd * g1.y + b1v.y);
  o8[6] = (__bf16)__float2bfloat16((v1.z - mean) * rstd * g1.z + b1v.z);
  o8[7] = (__bf16)__float2bfloat16((v1.w - mean) * rstd * g1.w + b1v.w);
  *(bf16x8*)(out + ((size_t)(row >> 4) * 16 + (lane >> 2)) * 512 + (row & 15) * 8 + 128 * (lane & 3)) = o8;
}

// ---------------- frag GEMM (round-5): C[M,N] = A * BT^T + bias, no LDS, no barriers ----------------
// A frag-tiled [M/16][K/32][512]; BT frag-tiled [N/16][K/32][512].
// MODE 0: out bf16 frag-tiled (KT_out = N/32).
// MODE 1: out fp32 row-major = resid + acc + bias (N==512).
// MODE 2: ReGLU: paired cols (a=even,b=odd), out bf16 frag-tiled [M/16][(N/2)/32][512].
template <int MODE>
__global__ __launch_bounds__(256, 3) void gemm_frag(const bf16_t* __restrict__ A,
    const bf16_t* __restrict__ BT, const float* __restrict__ bias, int biasN,
    const float* __restrict__ resid, void* __restrict__ outp, int K, int N)
{
  // XCD-aware remap: blocks with lin%8==x get a contiguous idx chunk
  const int total = gridDim.x * gridDim.y;
  const int lin = blockIdx.y * gridDim.x + blockIdx.x;
  const int xcd = lin & 7, kb2 = lin >> 3;
  const int qch = total >> 3, rch = total & 7;
  const int idx = xcd * qch + (xcd < rch ? xcd : rch) + kb2;
  const int bm = idx / gridDim.x;
  const int bn = idx - bm * gridDim.x;
  const int m0 = bm * 128, n0 = bn * 128;

  const int tid = threadIdx.x;
  const int w = tid >> 6, l = tid & 63, l15 = l & 15, quad = l >> 4;
  const int wm = (w >> 1) * 64, wn = (w & 1) * 64;
  const int KT = K >> 5;

  const bf16_t* pa[4];
  const bf16_t* pb[4];
  #pragma unroll
  for (int i = 0; i < 4; i++) {
    pa[i] = A  + ((size_t)(((m0 + wm) >> 4) + i) * KT) * 512 + l * 8;
    pb[i] = BT + ((size_t)(((n0 + wn) >> 4) + i) * KT) * 512 + l * 8;
  }

  bf16x8 af[2][4], bg[2][4];
  #pragma unroll
  for (int i = 0; i < 4; i++) {
    af[0][i] = *(const bf16x8*)pa[i];
    bg[0][i] = *(const bf16x8*)pb[i];
  }

  floatx4 z4 = {0.f, 0.f, 0.f, 0.f};
  floatx4 acc[4][4];
  #pragma unroll
  for (int i = 0; i < 4; i++)
    #pragma unroll
    for (int j = 0; j < 4; j++) acc[i][j] = z4;

  const int T = KT;  // 16 or 22, always even
  for (int t = 0; t < T; t += 2) {
    if (t + 1 < T) {
      #pragma unroll
      for (int i = 0; i < 4; i++) {
        af[1][i] = *(const bf16x8*)(pa[i] + (size_t)(t + 1) * 512);
        bg[1][i] = *(const bf16x8*)(pb[i] + (size_t)(t + 1) * 512);
      }
    }
    #pragma unroll
    for (int i = 0; i < 4; i++)
      #pragma unroll
      for (int j = 0; j < 4; j++)
        acc[i][j] = mfma16(af[0][i], bg[0][j], acc[i][j]);
    if (t + 1 < T) {
      if (t + 2 < T) {
        #pragma unroll
        for (int i = 0; i < 4; i++) {
          af[0][i] = *(const bf16x8*)(pa[i] + (size_t)(t + 2) * 512);
          bg[0][i] = *(const bf16x8*)(pb[i] + (size_t)(t + 2) * 512);
        }
      }
      #pragma unroll
      for (int i = 0; i < 4; i++)
        #pragma unroll
        for (int j = 0; j < 4; j++)
          acc[i][j] = mfma16(af[1][i], bg[1][j], acc[i][j]);
    }
  }

  #pragma unroll
  for (int j = 0; j < 4; j++) {
    int col = n0 + wn + j * 16 + l15;
    float bv = 0.f;
    if (MODE == 2) {
      if (col < biasN) bv = bias[(col & 1) ? 682 + (col >> 1) : (col >> 1)];
    } else {
      if (col < biasN) bv = bias[col];
    }
    #pragma unroll
    for (int i = 0; i < 4; i++) {
      int row_b = m0 + wm + i * 16 + quad * 4;
      #pragma unroll
      for (int r = 0; r < 4; r++) {
        float v = acc[i][j][r] + bv;
        int m = row_b + r;
        if (MODE == 2) {
          float other = __shfl_xor(v, 1);
          if (!(l15 & 1)) {
            int c2 = col >> 1;
            ((bf16_t*)outp)[frag_elem(m, c2, (N >> 1) >> 5)] =
                __float2bfloat16(v * fmaxf(other, 0.f));
          }
        } else if (MODE == 1) {
          size_t idx2 = (size_t)m * N + col;
          ((float*)outp)[idx2] = v + resid[idx2];
        } else {
          ((bf16_t*)outp)[frag_elem(m, col, N >> 5)] = __float2bfloat16(v);
        }
      }
    }
  }
}

// ---------------- fused attention v2: wave-independent ----------------
// Block = 320 threads (5 waves); grid 1024 = (batch, head). Wave w owns q-tile w
// (rows w*32..w*32+31). V^T staged in shared LDS once (2 barriers); each wave has a
// private P strip. No barriers in the compute phase.
constexpr int SPP = 168;  // padded col stride: 336B == 20 words mod 32 -> conflict-free
__global__ __launch_bounds__(320) void attn_kernel(const bf16_t* __restrict__ qkv,
                                                   bf16_t* __restrict__ attnout)
{
  __shared__ __align__(16) __bf16 vt_lds[64 * SPP];      // [d][s]   21.5 KB
  __shared__ __align__(16) __bf16 p_lds[5][32 * SPP];    // per-wave 53.8 KB

  const int bh = blockIdx.x, b = bh >> 3, hh = bh & 7;
  const int tid = threadIdx.x;
  const int w = tid / 64, l = tid & 63, l15 = l & 15, quad = l >> 4;
  const int rbase = b * 129;

  // zero V^T (covers s>=129 pad), stage V^T from qkv frag layout
  for (int i = tid; i < 64 * SPP / 2; i += 320) ((unsigned int*)vt_lds)[i] = 0u;
  __syncthreads();
  for (int c = tid; c < 129 * 8; c += 320) {
    int s = c >> 3, ch = c & 7;
    bf16x8 tv = *(const bf16x8*)(qkv + frag_chunk(rbase + s, hh * 192 + 128 + ch * 8, 48));
    #pragma unroll
    for (int j = 0; j < 8; j++) vt_lds[(size_t)(ch * 8 + j) * SPP + s] = tv[j];
  }
  __syncthreads();

  const int qt = w;                 // wave's q-tile (0..4)
  __bf16* pw = p_lds[w];

  // ---- load Q fragments ----
  bf16x8 zq = {};
  bf16x8 aq[2][2];
  #pragma unroll
  for (int mt = 0; mt < 2; mt++) {
    int m = qt * 32 + mt * 16 + l15;
    #pragma unroll
    for (int t = 0; t < 2; t++)
      aq[mt][t] = (m < 129)
          ? *(const bf16x8*)(qkv + frag_chunk(rbase + m, hh * 192 + t * 32 + quad * 8, 48)) : zq;
  }

  // ---- QK^T: 9 n-tiles (cols 0..143; col>=129 masked later; n-tile 9 is all-pad) ----
  floatx4 z4 = {0.f, 0.f, 0.f, 0.f};
  floatx4 sc[2][9];
  #pragma unroll
  for (int mt = 0; mt < 2; mt++)
    #pragma unroll
    for (int nt = 0; nt < 9; nt++) sc[mt][nt] = z4;
  #pragma unroll
  for (int nt = 0; nt < 9; nt++) {
    int krow = nt * 16 + l15;
    #pragma unroll
    for (int t = 0; t < 2; t++) {
      bf16x8 kf = (krow < 129)
          ? *(const bf16x8*)(qkv + frag_chunk(rbase + krow, hh * 192 + 64 + t * 32 + quad * 8, 48))
          : zq;
      sc[0][nt] = mfma16(aq[0][t], kf, sc[0][nt]);
      sc[1][nt] = mfma16(aq[1][t], kf, sc[1][nt]);
    }
  }

  // ---- in-register double softmax per row; write P (bf16) to wave-private LDS ----
  // Row of (mt, r): values live in 16 lanes (l15) x 9 regs. col = nt*16+l15;
  // valid iff nt<8 or (nt==8 && l15==0)  (129 cols).
  const bool v8 = (l15 == 0);
  #pragma unroll
  for (int mt = 0; mt < 2; mt++) {
    #pragma unroll
    for (int r = 0; r < 4; r++) {
      float v[9];
      #pragma unroll
      for (int nt = 0; nt < 9; nt++) v[nt] = sc[mt][nt][r] * SQRT_EMB_F;
      float mx = -1e30f;
      #pragma unroll
      for (int nt = 0; nt < 8; nt++) mx = fmaxf(mx, v[nt]);
      if (v8) mx = fmaxf(mx, v[8]);
      #pragma unroll
      for (int o = 1; o < 16; o <<= 1) mx = fmaxf(mx, __shfl_xor(mx, o));
      float sum = 0.f;
      #pragma unroll
      for (int nt = 0; nt < 8; nt++) { v[nt] = __expf(v[nt] - mx); sum += v[nt]; }
      v[8] = v8 ? __expf(v[8] - mx) : 0.f;
      sum += v[8];
      #pragma unroll
      for (int o = 1; o < 16; o <<= 1) sum += __shfl_xor(sum, o);
      float inv = 1.f / sum;
      float mx2 = 0.f;
      #pragma unroll
      for (int nt = 0; nt < 9; nt++) { v[nt] *= inv; mx2 = fmaxf(mx2, v[nt]); }
      #pragma unroll
      for (int o = 1; o < 16; o <<= 1) mx2 = fmaxf(mx2, __shfl_xor(mx2, o));
      float sum2 = 0.f;
      #pragma unroll
      for (int nt = 0; nt < 8; nt++) { v[nt] = __expf(v[nt] - mx2); sum2 += v[nt]; }
      v[8] = v8 ? __expf(v[8] - mx2) : 0.f;
      sum2 += v[8];
      #pragma unroll
      for (int o = 1; o < 16; o <<= 1) sum2 += __shfl_xor(sum2, o);
      float inv2 = 1.f / sum2;
      int row = mt * 16 + quad * 4 + r;
      #pragma unroll
      for (int nt = 0; nt < 9; nt++) {
        float pv = (nt < 8 || v8) ? v[nt] * inv2 : 0.f;
        pw[(size_t)row * SPP + nt * 16 + l15] = __bf16(__float2bfloat16(pv));
      }
      pw[(size_t)row * SPP + 144 + l15] = __bf16(0.0f);   // n-tile 9 (cols 144..159) = 0
    }
  }
  asm volatile("" ::: "memory");   // LDS writes before reads (same wave; no barrier needed)

  // ---- PV: o[32,64] = P[32,160] @ V[160,64] ----
  floatx4 oacc[2][4];
  #pragma unroll
  for (int mt = 0; mt < 2; mt++)
    #pragma unroll
    for (int dt = 0; dt < 4; dt++) oacc[mt][dt] = z4;
  #pragma unroll
  for (int kt = 0; kt < 5; kt++) {
    bf16x8 pf[2], vf[4];
    #pragma unroll
    for (int mt = 0; mt < 2; mt++)
      pf[mt] = *(const bf16x8*)&pw[(size_t)(mt * 16 + l15) * SPP + kt * 32 + quad * 8];
    #pragma unroll
    for (int dt = 0; dt < 4; dt++)
      vf[dt] = *(const bf16x8*)&vt_lds[(size_t)(dt * 16 + l15) * SPP + kt * 32 + quad * 8];
    #pragma unroll
    for (int mt = 0; mt < 2; mt++)
      #pragma unroll
      for (int dt = 0; dt < 4; dt++)
        oacc[mt][dt] = mfma16(pf[mt], vf[dt], oacc[mt][dt]);
  }
  #pragma unroll
  for (int mt = 0; mt < 2; mt++)
    #pragma unroll
    for (int dt = 0; dt < 4; dt++)
      #pragma unroll
      for (int r = 0; r < 4; r++) {
        int sq = qt * 32 + mt * 16 + quad * 4 + r;
        if (sq < 129) {
          int cc = hh * 64 + dt * 16 + l15;
          attnout[frag_elem(rbase + sq, cc, 16)] = __float2bfloat16(oacc[mt][dt][r]);
        }
      }
}

// ---------------- output: CLS rows ----------------
__global__ __launch_bounds__(256) void out_copy(const float* __restrict__ h,
                                                float* __restrict__ out)
{
  int b = blockIdx.x, e = threadIdx.x;
  out[(size_t)b * 512 + e]       = h[(size_t)b * 129 * 512 + e];
  out[(size_t)b * 512 + e + 256] = h[(size_t)b * 129 * 512 + e + 256];
}

// ---------------- host launcher ----------------
extern "C" void kernel_launch(void* const* d_in, const int* in_sizes, int n_in,
                              void* d_out, int out_size, void* d_ws, size_t ws_size,
                              hipStream_t stream)
{
  const float* x       = (const float*)d_in[0];
  const float* tok_w   = (const float*)d_in[1];
  const float* tok_b   = (const float*)d_in[2];
  const float* cat_emb = (const float*)d_in[3];
  const float* Wqkv    = (const float*)d_in[4];
  const float* bqkv    = (const float*)d_in[5];
  const float* Wout    = (const float*)d_in[6];
  const float* bout    = (const float*)d_in[7];
  const float* W0      = (const float*)d_in[8];
  const float* b0      = (const float*)d_in[9];
  const float* W1      = (const float*)d_in[10];
  const float* b1      = (const float*)d_in[11];
  const float* ln0_g   = (const float*)d_in[12];
  const float* ln0_b   = (const float*)d_in[13];
  const float* ln1_g   = (const float*)d_in[14];
  const float* ln1_b   = (const float*)d_in[15];

  size_t off = 0;
  char* base = (char*)d_ws;
  auto alloc = [&](size_t n) { char* p = base + off; off += (n + 255) & ~(size_t)255; return p; };
  float*  h     = (float*) alloc((size_t)M_ROWS * 512 * 4);
  bf16_t* ab    = (bf16_t*)alloc((size_t)M_ROWS * 512 * 2);   // LN out, frag KT=16
  bf16_t* qkv   = (bf16_t*)alloc((size_t)M_ROWS * 1536 * 2);  // frag KT=48
  bf16_t* attno = (bf16_t*)alloc((size_t)M_ROWS * 512 * 2);   // frag KT=16
  bf16_t* regl  = (bf16_t*)alloc((size_t)M_ROWS * 704 * 2);   // frag KT=22
  bf16_t* WqkvT = (bf16_t*)alloc((size_t)6 * 1536 * 512 * 2);
  bf16_t* WoutT = (bf16_t*)alloc((size_t)6 * 512 * 512 * 2);
  bf16_t* W0T   = (bf16_t*)alloc((size_t)6 * 1408 * 512 * 2);  // pair-interleaved
  bf16_t* W1T   = (bf16_t*)alloc((size_t)6 * 512 * 704 * 2);
  (void)ws_size; (void)in_sizes; (void)n_in; (void)out_size;

  dim3 tb(32, 8, 1);
  transpose_cvt<0><<<dim3(16, 48, 6), tb, 0, stream>>>(Wqkv, WqkvT, 512, 1536, 512, 1536);
  transpose_cvt<0><<<dim3(16, 16, 6), tb, 0, stream>>>(Wout, WoutT, 512, 512, 512, 512);
  transpose_cvt<1><<<dim3(16, 44, 6), tb, 0, stream>>>(W0, W0T, 512, 1364, 512, 1408);
  transpose_cvt<0><<<dim3(22, 16, 6), tb, 0, stream>>>(W1, W1T, 682, 512, 704, 512);

  tokenizer_kernel<<<M_ROWS / 4, 256, 0, stream>>>(x, tok_w, tok_b, cat_emb, h, ab);

  for (int i = 0; i < 6; i++) {
    if (i)
      ln_kernel<<<M_ROWS / 4, 256, 0, stream>>>(h, ab, ln0_g + (size_t)i * 512,
                                                ln0_b + (size_t)i * 512);
    gemm_frag<0><<<dim3(12, 129), 256, 0, stream>>>(
        ab, WqkvT + (size_t)i * 1536 * 512, bqkv + (size_t)i * 1536, 1536, nullptr, qkv, 512, 1536);
    attn_kernel<<<1024, 320, 0, stream>>>(qkv, attno);
    gemm_frag<1><<<dim3(4, 129), 256, 0, stream>>>(
        attno, WoutT + (size_t)i * 512 * 512, bout + (size_t)i * 512, 512, h, h, 512, 512);
    ln_kernel<<<M_ROWS / 4, 256, 0, stream>>>(h, ab, ln1_g + (size_t)i * 512,
                                              ln1_b + (size_t)i * 512);
    gemm_frag<2><<<dim3(11, 129), 256, 0, stream>>>(
        ab, W0T + (size_t)i * 1408 * 512, b0 + (size_t)i * 1364, 1364, nullptr, regl, 512, 1408);
    gemm_frag<1><<<dim3(4, 129), 256, 0, stream>>>(
        regl, W1T + (size_t)i * 512 * 704, b1 + (size_t)i * 512, 512, h, h, 704, 512);
  }

  out_copy<<<128, 256, 0, stream>>>(h, (float*)d_out);
}